// Round 6
// baseline (2470.048 us; speedup 1.0000x reference)
//
#include <hip/hip_runtime.h>
#include <math.h>

#define NN 100000
#define NE 1600000
#define DD 32
#define CC 16

typedef unsigned short bf16_t;
struct us4 { bf16_t x, y, z, w; };

static inline unsigned gblocks(long total) { return (unsigned)((total + 255) / 256); }

__device__ inline bf16_t f2bf(float f) {
    unsigned u = __float_as_uint(f);
    u += 0x7fffu + ((u >> 16) & 1u);
    return (bf16_t)(u >> 16);
}
__device__ inline float bf2f(bf16_t h) { return __uint_as_float(((unsigned)h) << 16); }

__global__ void zero_k(float* p, long n) {
    long i = (long)blockIdx.x * 256 + threadIdx.x;
    if (i < n) p[i] = 0.f;
}

__global__ void count_k(const int* __restrict__ dst, float* __restrict__ cnt) {
    int e = blockIdx.x * 256 + threadIdx.x;
    if (e < NE) atomicAdd(&cnt[dst[e]], 1.0f);
}

// y[n][k][e] = x[n,:] @ W[k][:,e], bf16 out.
// Block = 128-node tile; x staged in LDS ONCE, then loop over all K inside
// (fixes round-3/4's 157MB FETCH: x was re-read once per k-plane).
template<int K>
__global__ __launch_bounds__(256) void yk_k(const float* __restrict__ x,
                                            const float* __restrict__ W,
                                            us4* __restrict__ y) {
    __shared__ float xs[128 * 36];
    const long n0 = (long)blockIdx.x * 128;
    const int tid = threadIdx.x;

#pragma unroll
    for (int i = 0; i < 4; ++i) {
        int idx = tid + 256 * i;
        int row = idx >> 3;
        int c4 = idx & 7;
        long n = n0 + row;
        float4 v = make_float4(0.f, 0.f, 0.f, 0.f);
        if (n < NN) v = ((const float4*)x)[n * 8 + c4];
        *(float4*)&xs[row * 36 + c4 * 4] = v;
    }
    __syncthreads();

    const int eq = tid & 7;   // output-dim quad
    const int nl = tid >> 3;  // node lane 0..31

    for (int k = 0; k < K; ++k) {
        const float4* Wk = (const float4*)(W + (long)k * DD * DD) + eq;
        float4 a0 = make_float4(0, 0, 0, 0), a1 = a0, a2 = a0, a3 = a0;
#pragma unroll
        for (int d4 = 0; d4 < 8; ++d4) {
            float4 w0 = Wk[(4 * d4 + 0) * 8];
            float4 w1 = Wk[(4 * d4 + 1) * 8];
            float4 w2 = Wk[(4 * d4 + 2) * 8];
            float4 w3 = Wk[(4 * d4 + 3) * 8];
#pragma unroll
            for (int j = 0; j < 4; ++j) {
                float4 xv = *(const float4*)&xs[(nl + 32 * j) * 36 + d4 * 4];
                float4& a = j == 0 ? a0 : j == 1 ? a1 : j == 2 ? a2 : a3;
                a.x = fmaf(xv.x, w0.x, a.x); a.y = fmaf(xv.x, w0.y, a.y);
                a.z = fmaf(xv.x, w0.z, a.z); a.w = fmaf(xv.x, w0.w, a.w);
                a.x = fmaf(xv.y, w1.x, a.x); a.y = fmaf(xv.y, w1.y, a.y);
                a.z = fmaf(xv.y, w1.z, a.z); a.w = fmaf(xv.y, w1.w, a.w);
                a.x = fmaf(xv.z, w2.x, a.x); a.y = fmaf(xv.z, w2.y, a.y);
                a.z = fmaf(xv.z, w2.z, a.z); a.w = fmaf(xv.z, w2.w, a.w);
                a.x = fmaf(xv.w, w3.x, a.x); a.y = fmaf(xv.w, w3.y, a.y);
                a.z = fmaf(xv.w, w3.z, a.z); a.w = fmaf(xv.w, w3.w, a.w);
            }
        }
#pragma unroll
        for (int j = 0; j < 4; ++j) {
            long n = n0 + nl + 32 * j;
            if (n >= NN) continue;
            float4 a = j == 0 ? a0 : j == 1 ? a1 : j == 2 ? a2 : a3;
            us4 o; o.x = f2bf(a.x); o.y = f2bf(a.y); o.z = f2bf(a.z); o.w = f2bf(a.w);
            y[(n * K + k) * 8 + eq] = o;
        }
    }
}

// per (edge, e): 4-tap bilinear blend of gathered bf16 y rows, atomic scatter
template<int KS>
__global__ void edge_y_k(const int* __restrict__ src, const int* __restrict__ dst,
                         const float* __restrict__ attr, const bf16_t* __restrict__ y,
                         float* __restrict__ agg) {
    long tid = (long)blockIdx.x * 256 + threadIdx.x;
    if (tid >= (long)NE * DD) return;
    int e = (int)(tid & (DD - 1));
    int ed = (int)(tid >> 5);
    const int K = KS * KS;
    float u0 = attr[2 * ed], u1 = attr[2 * ed + 1];
    float v0 = u0 * (KS - 1), v1 = u1 * (KS - 1);
    float fb0 = floorf(v0), fb1 = floorf(v1);
    float f0 = v0 - fb0, f1 = v1 - fb1;
    int i0 = min((int)fb0, KS - 1), i1 = min((int)fb1, KS - 1);
    int j0 = min(i0 + 1, KS - 1), j1 = min(i1 + 1, KS - 1);
    int s = src[ed];
    long base = (long)s * K * DD + e;
    float y00 = bf2f(y[base + (i0 + i1 * KS) * DD]);
    float y10 = bf2f(y[base + (j0 + i1 * KS) * DD]);
    float y01 = bf2f(y[base + (i0 + j1 * KS) * DD]);
    float y11 = bf2f(y[base + (j0 + j1 * KS) * DD]);
    float m = (1.f - f0) * (1.f - f1) * y00 + f0 * (1.f - f1) * y10
            + (1.f - f0) * f1 * y01 + f0 * f1 * y11;
    atomicAdd(&agg[(long)dst[ed] * DD + e], m);
}

// h[n,e] = elu(agg/max(cnt,1) + x@root + bias); root matvec via shfl
__global__ __launch_bounds__(256) void fin_k(
        const float* __restrict__ agg, const float* __restrict__ cnt,
        const float* __restrict__ xin, const float* __restrict__ root,
        const float* __restrict__ bias, float* __restrict__ h) {
    const int lane = threadIdx.x & 31;
    const int grp = threadIdx.x >> 5;
    const int n = blockIdx.x * 8 + grp;
    if (n >= NN) return;
    float c = cnt[n]; if (c < 1.f) c = 1.f;
    float xv = xin[(long)n * DD + lane];
    float racc = 0.f;
#pragma unroll
    for (int d = 0; d < DD; ++d)
        racc = fmaf(__shfl(xv, d, 32), root[d * DD + lane], racc);
    float v = agg[(long)n * DD + lane] / c + racc + bias[lane];
    h[(long)n * DD + lane] = v > 0.f ? v : expm1f(v);
}

// fused 2-layer MLP head: one 32-lane group per node
__global__ __launch_bounds__(256) void mlp_k(
        const float* __restrict__ h, const float* __restrict__ w1,
        const float* __restrict__ b1, const float* __restrict__ w2,
        const float* __restrict__ b2, float* __restrict__ out) {
    const int lane = threadIdx.x & 31;
    const int grp = threadIdx.x >> 5;
    const int n = blockIdx.x * 8 + grp;
    if (n >= NN) return;
    float hv = h[(long)n * DD + lane];
    float t = b1[lane];
#pragma unroll
    for (int d = 0; d < DD; ++d)
        t = fmaf(__shfl(hv, d, 32), w1[d * DD + lane], t);
    t = fmaxf(t, 0.f);
    int c = lane & (CC - 1);
    float o = 0.f;
#pragma unroll
    for (int d = 0; d < DD; ++d)
        o = fmaf(__shfl(t, d, 32), w2[d * CC + c], o);
    o += b2[c];
    o = fmaxf(o, 0.f);
    if (lane < CC) out[(long)n * CC + lane] = o;
}

extern "C" void kernel_launch(void* const* d_in, const int* in_sizes, int n_in,
                              void* d_out, int out_size, void* d_ws, size_t ws_size,
                              hipStream_t stream) {
    const float* x     = (const float*)d_in[0];
    const int*   ei    = (const int*)d_in[1];
    const float* attr  = (const float*)d_in[2];
    const float* W1    = (const float*)d_in[3];
    const float* root1 = (const float*)d_in[4];
    const float* bias1 = (const float*)d_in[5];
    const float* W2    = (const float*)d_in[6];
    const float* root2 = (const float*)d_in[7];
    const float* bias2 = (const float*)d_in[8];
    const float* m1w   = (const float*)d_in[9];
    const float* m1b   = (const float*)d_in[10];
    const float* m2w   = (const float*)d_in[11];
    const float* m2b   = (const float*)d_in[12];
    float* out = (float*)d_out;

    const int* srcp = ei;
    const int* dstp = ei + NE;

    // ws: cnt(NN) | agg(NN*32) | h1 | h2 | y bf16(NN*25*32)  => 198.8 MB total
    float* cnt = (float*)d_ws;
    float* agg = cnt + NN;
    float* h1  = agg + (size_t)NN * DD;
    float* h2  = h1 + (size_t)NN * DD;
    bf16_t* y  = (bf16_t*)(h2 + (size_t)NN * DD);

    const unsigned gy = (NN + 127) / 128;
    const unsigned gn = (NN + 7) / 8;

    zero_k<<<gblocks(NN + (long)NN * DD), 256, 0, stream>>>(cnt, NN + (long)NN * DD);
    count_k<<<gblocks(NE), 256, 0, stream>>>(dstp, cnt);

    // ---- layer 1 (ksize=3, K=9) ----
    yk_k<9><<<gy, 256, 0, stream>>>(x, W1, (us4*)y);
    edge_y_k<3><<<gblocks((long)NE * DD), 256, 0, stream>>>(srcp, dstp, attr, y, agg);
    fin_k<<<gn, 256, 0, stream>>>(agg, cnt, x, root1, bias1, h1);

    // ---- layer 2 (ksize=5, K=25) ----
    zero_k<<<gblocks((long)NN * DD), 256, 0, stream>>>(agg, (long)NN * DD);
    yk_k<25><<<gy, 256, 0, stream>>>(h1, W2, (us4*)y);
    edge_y_k<5><<<gblocks((long)NE * DD), 256, 0, stream>>>(srcp, dstp, attr, y, agg);
    fin_k<<<gn, 256, 0, stream>>>(agg, cnt, h1, root2, bias2, h2);

    // ---- fused MLP head ----
    mlp_k<<<gn, 256, 0, stream>>>(h2, m1w, m1b, m2w, m2b, out);
}

// Round 7
// 974.939 us; speedup vs baseline: 2.5335x; 2.5335x over previous
//
#include <hip/hip_runtime.h>
#include <math.h>

#define NN 100000
#define NE 1600000
#define DD 32
#define CC 16

typedef unsigned short bf16_t;

static inline unsigned gblocks(long total) { return (unsigned)((total + 255) / 256); }

__device__ inline bf16_t f2bf(float f) {
    unsigned u = __float_as_uint(f);
    u += 0x7fffu + ((u >> 16) & 1u);
    return (bf16_t)(u >> 16);
}
__device__ inline float bf2f(bf16_t h) { return __uint_as_float(((unsigned)h) << 16); }

__global__ void zero_k(float* p, long n) {
    long i = (long)blockIdx.x * 256 + threadIdx.x;
    if (i < n) p[i] = 0.f;
}

__global__ void count_k(const int* __restrict__ dst, float* __restrict__ cnt) {
    int e = blockIdx.x * 256 + threadIdx.x;
    if (e < NE) atomicAdd(&cnt[dst[e]], 1.0f);
}

// y[n][k][e] = x[n,:] @ W[k][:,e], bf16, row stride KP (padded so each k-pair
// chunk is a 128B-aligned full line).  thread = node: x row in 32 VGPRs; W
// read via wave-uniform addresses -> SGPR broadcast (zero VMEM bandwidth);
// only acc[32] live (no spill).  Stores staged in LDS, written back as
// perfectly coalesced full lines (fixes 64B-store RMW: FETCH==WRITE in r3/4/6).
template<int K, int KP>
__global__ __launch_bounds__(64, 4) void ysg_k(const float* __restrict__ x,
                                               const float* __restrict__ W,
                                               unsigned* __restrict__ y) {
    __shared__ unsigned lds[64 * 33];
    const int tid = threadIdx.x;
    const long n0 = (long)blockIdx.x * 64;
    const long n = n0 + tid;

    float xr[DD];
    {
        const float4* xp = (const float4*)(x + (n < NN ? n : (NN - 1)) * DD);
#pragma unroll
        for (int i = 0; i < 8; ++i) {
            float4 v = xp[i];
            xr[4 * i + 0] = v.x; xr[4 * i + 1] = v.y;
            xr[4 * i + 2] = v.z; xr[4 * i + 3] = v.w;
        }
    }

    constexpr int NP = (K + 1) / 2;          // k-pairs
    constexpr int H0 = (NP + 1) / 2;         // split across blockIdx.y
    const int p0 = blockIdx.y == 0 ? 0 : H0;
    const int p1 = blockIdx.y == 0 ? H0 : NP;

    for (int kp = p0; kp < p1; ++kp) {
#pragma unroll
        for (int half = 0; half < 2; ++half) {
            const int k = 2 * kp + half;
            if (k < K) {
                const float* Wk = W + (long)k * (DD * DD);
                float acc[DD];
#pragma unroll
                for (int e = 0; e < DD; ++e) acc[e] = 0.f;
#pragma unroll
                for (int d = 0; d < DD; ++d) {
                    const float xd = xr[d];
                    const float* wr = Wk + d * DD;   // wave-uniform -> s_load
#pragma unroll
                    for (int e = 0; e < DD; ++e)
                        acc[e] = fmaf(xd, wr[e], acc[e]);
                }
                // pack 32 f32 -> 16 dwords into LDS row (banks <=2-way, pad 33)
#pragma unroll
                for (int i = 0; i < 16; ++i) {
                    unsigned dw = (unsigned)f2bf(acc[2 * i]) |
                                  ((unsigned)f2bf(acc[2 * i + 1]) << 16);
                    lds[tid * 33 + half * 16 + i] = dw;
                }
            }
        }
        __syncthreads();
        // writeback: 64 nodes x 32 dwords; consecutive lanes -> consecutive
        // dwords -> full 128B lines (row base n*KP*64B is 128B-aligned)
#pragma unroll
        for (int it = 0; it < 32; ++it) {
            int idx = it * 64 + tid;
            int node = idx >> 5;
            int dw = idx & 31;
            long gn = n0 + node;
            if (gn < NN)
                y[gn * (KP * 16) + (long)kp * 32 + dw] = lds[node * 33 + dw];
        }
        __syncthreads();
    }
}

// per (edge, e): 4-tap bilinear blend of gathered bf16 y rows, atomic scatter
template<int KS, int KP>
__global__ void edge_y_k(const int* __restrict__ src, const int* __restrict__ dst,
                         const float* __restrict__ attr, const bf16_t* __restrict__ y,
                         float* __restrict__ agg) {
    long tid = (long)blockIdx.x * 256 + threadIdx.x;
    if (tid >= (long)NE * DD) return;
    int e = (int)(tid & (DD - 1));
    int ed = (int)(tid >> 5);
    float u0 = attr[2 * ed], u1 = attr[2 * ed + 1];
    float v0 = u0 * (KS - 1), v1 = u1 * (KS - 1);
    float fb0 = floorf(v0), fb1 = floorf(v1);
    float f0 = v0 - fb0, f1 = v1 - fb1;
    int i0 = min((int)fb0, KS - 1), i1 = min((int)fb1, KS - 1);
    int j0 = min(i0 + 1, KS - 1), j1 = min(i1 + 1, KS - 1);
    int s = src[ed];
    long base = (long)s * (KP * DD) + e;
    float y00 = bf2f(y[base + (i0 + i1 * KS) * DD]);
    float y10 = bf2f(y[base + (j0 + i1 * KS) * DD]);
    float y01 = bf2f(y[base + (i0 + j1 * KS) * DD]);
    float y11 = bf2f(y[base + (j0 + j1 * KS) * DD]);
    float m = (1.f - f0) * (1.f - f1) * y00 + f0 * (1.f - f1) * y10
            + (1.f - f0) * f1 * y01 + f0 * f1 * y11;
    atomicAdd(&agg[(long)dst[ed] * DD + e], m);
}

// h[n,e] = elu(agg/max(cnt,1) + x@root + bias); root matvec via shfl
__global__ __launch_bounds__(256) void fin_k(
        const float* __restrict__ agg, const float* __restrict__ cnt,
        const float* __restrict__ xin, const float* __restrict__ root,
        const float* __restrict__ bias, float* __restrict__ h) {
    const int lane = threadIdx.x & 31;
    const int grp = threadIdx.x >> 5;
    const int n = blockIdx.x * 8 + grp;
    if (n >= NN) return;
    float c = cnt[n]; if (c < 1.f) c = 1.f;
    float xv = xin[(long)n * DD + lane];
    float racc = 0.f;
#pragma unroll
    for (int d = 0; d < DD; ++d)
        racc = fmaf(__shfl(xv, d, 32), root[d * DD + lane], racc);
    float v = agg[(long)n * DD + lane] / c + racc + bias[lane];
    h[(long)n * DD + lane] = v > 0.f ? v : expm1f(v);
}

// fused 2-layer MLP head: one 32-lane group per node
__global__ __launch_bounds__(256) void mlp_k(
        const float* __restrict__ h, const float* __restrict__ w1,
        const float* __restrict__ b1, const float* __restrict__ w2,
        const float* __restrict__ b2, float* __restrict__ out) {
    const int lane = threadIdx.x & 31;
    const int grp = threadIdx.x >> 5;
    const int n = blockIdx.x * 8 + grp;
    if (n >= NN) return;
    float hv = h[(long)n * DD + lane];
    float t = b1[lane];
#pragma unroll
    for (int d = 0; d < DD; ++d)
        t = fmaf(__shfl(hv, d, 32), w1[d * DD + lane], t);
    t = fmaxf(t, 0.f);
    int c = lane & (CC - 1);
    float o = 0.f;
#pragma unroll
    for (int d = 0; d < DD; ++d)
        o = fmaf(__shfl(t, d, 32), w2[d * CC + c], o);
    o += b2[c];
    o = fmaxf(o, 0.f);
    if (lane < CC) out[(long)n * CC + lane] = o;
}

extern "C" void kernel_launch(void* const* d_in, const int* in_sizes, int n_in,
                              void* d_out, int out_size, void* d_ws, size_t ws_size,
                              hipStream_t stream) {
    const float* x     = (const float*)d_in[0];
    const int*   ei    = (const int*)d_in[1];
    const float* attr  = (const float*)d_in[2];
    const float* W1    = (const float*)d_in[3];
    const float* root1 = (const float*)d_in[4];
    const float* bias1 = (const float*)d_in[5];
    const float* W2    = (const float*)d_in[6];
    const float* root2 = (const float*)d_in[7];
    const float* bias2 = (const float*)d_in[8];
    const float* m1w   = (const float*)d_in[9];
    const float* m1b   = (const float*)d_in[10];
    const float* m2w   = (const float*)d_in[11];
    const float* m2b   = (const float*)d_in[12];
    float* out = (float*)d_out;

    const int* srcp = ei;
    const int* dstp = ei + NE;

    // ws: cnt(NN) | agg(NN*32) | h1(NN*32) | y bf16 (NN*26*32) ; h2 overlays y
    // total 0.4 + 12.8 + 12.8 + 166.4 = 192.4 MB (<= proven 198.8 budget)
    float* cnt = (float*)d_ws;
    float* agg = cnt + NN;
    float* h1  = agg + (size_t)NN * DD;
    bf16_t* y  = (bf16_t*)(h1 + (size_t)NN * DD);
    float* h2  = (float*)y;  // written only after edge<5> finished reading y

    const unsigned gy = (NN + 63) / 64;
    const unsigned gn = (NN + 7) / 8;

    zero_k<<<gblocks(NN + (long)NN * DD), 256, 0, stream>>>(cnt, NN + (long)NN * DD);
    count_k<<<gblocks(NE), 256, 0, stream>>>(dstp, cnt);

    // ---- layer 1 (ksize=3, K=9, padded stride 10) ----
    ysg_k<9, 10><<<dim3(gy, 2), 64, 0, stream>>>(x, W1, (unsigned*)y);
    edge_y_k<3, 10><<<gblocks((long)NE * DD), 256, 0, stream>>>(srcp, dstp, attr, y, agg);
    fin_k<<<gn, 256, 0, stream>>>(agg, cnt, x, root1, bias1, h1);

    // ---- layer 2 (ksize=5, K=25, padded stride 26) ----
    zero_k<<<gblocks((long)NN * DD), 256, 0, stream>>>(agg, (long)NN * DD);
    ysg_k<25, 26><<<dim3(gy, 2), 64, 0, stream>>>(h1, W2, (unsigned*)y);
    edge_y_k<5, 26><<<gblocks((long)NE * DD), 256, 0, stream>>>(srcp, dstp, attr, y, agg);
    fin_k<<<gn, 256, 0, stream>>>(agg, cnt, h1, root2, bias2, h2);

    // ---- fused MLP head ----
    mlp_k<<<gn, 256, 0, stream>>>(h2, m1w, m1b, m2w, m2b, out);
}

// Round 8
// 622.089 us; speedup vs baseline: 3.9706x; 1.5672x over previous
//
#include <hip/hip_runtime.h>
#include <math.h>

#define NN 100000
#define NE 1600000
#define DD 32
#define CC 16

typedef unsigned short bf16_t;
typedef __attribute__((ext_vector_type(8))) short short8v;
typedef __attribute__((ext_vector_type(4))) float float4v;

static inline unsigned gblocks(long total) { return (unsigned)((total + 255) / 256); }

__device__ inline bf16_t f2bf(float f) {
    unsigned u = __float_as_uint(f);
    u += 0x7fffu + ((u >> 16) & 1u);
    return (bf16_t)(u >> 16);
}
__device__ inline float bf2f(bf16_t h) { return __uint_as_float(((unsigned)h) << 16); }
__device__ inline unsigned pk2(float a, float b) {
    return (unsigned)f2bf(a) | ((unsigned)f2bf(b) << 16);
}

__global__ void zero_k(float* p, long n) {
    long i = (long)blockIdx.x * 256 + threadIdx.x;
    if (i < n) p[i] = 0.f;
}

__global__ void count_k(const int* __restrict__ dst, float* __restrict__ cnt) {
    int e = blockIdx.x * 256 + threadIdx.x;
    if (e < NE) atomicAdd(&cnt[dst[e]], 1.0f);
}

// x (f32 [NN][32]) -> B-fragment-layout bf16: xtf[tile][lane][reg],
// lane = (n%16) + 16*(d/8), reg = d%8  (B[k][col]: col=lane&15, k=(lane>>4)*8+reg)
__global__ void castx_k(const float* __restrict__ in, bf16_t* __restrict__ outf) {
    int tid = blockIdx.x * 256 + threadIdx.x;  // (n, q): q = d-oct
    if (tid >= NN * 4) return;
    int n = tid >> 2, q = tid & 3;
    const float4* ip = (const float4*)(in + (long)n * DD + q * 8);
    float4 v0 = ip[0], v1 = ip[1];
    int tile = n >> 4;
    int lane = (n & 15) + 16 * q;
    unsigned* op = (unsigned*)(outf + ((long)tile * 64 + lane) * 8);
    op[0] = pk2(v0.x, v0.y);
    op[1] = pk2(v0.z, v0.w);
    op[2] = pk2(v1.x, v1.y);
    op[3] = pk2(v1.z, v1.w);
}

// W (f32 [K][32][32]) -> A-fragment-layout bf16 per (k, e-half):
// wtf[(k*2+half)*64 + lane][reg] = W[k][ 8*(lane>>4)+reg ][ (lane&15)+16*half ]
__global__ void castw_k(const float* __restrict__ W, bf16_t* __restrict__ wtf, int K) {
    int tid = blockIdx.x * 256 + threadIdx.x;
    if (tid >= K * 2 * 64) return;
    int l = tid & 63;
    int half = (tid >> 6) & 1;
    int k = tid >> 7;
    int e = (l & 15) + 16 * half;
    int dbase = (l >> 4) * 8;
    bf16_t* op = wtf + (long)tid * 8;
#pragma unroll
    for (int r = 0; r < 8; ++r)
        op[r] = f2bf(W[(long)k * 1024 + (dbase + r) * DD + e]);
}

// y[n][k][e] = x[n,:] @ W[k] via MFMA.  wave = one 16-node tile; B-frag (x)
// loaded once; loop k: 2 mfma_f32_16x16x32_bf16 (e-halves) vs L1-resident
// W-frags; pack f32->bf16; stage in LDS; write tile as ONE contiguous
// 16*K*64B block (all full lines).  D-map (m89): col=lane&15(node),
// row=(lane>>4)*4+reg (e within half).
template<int K>
__global__ __launch_bounds__(64) void ymm_k(const short8v* __restrict__ xtf,
                                            const short8v* __restrict__ wtf,
                                            unsigned* __restrict__ y) {
    constexpr int RS = K * 16 + 4;  // dword row stride per node (16B aligned, spread banks)
    __shared__ unsigned lds[16 * RS];
    const int l = threadIdx.x;
    const int tile = blockIdx.x;
    const int node = l & 15, g = l >> 4;

    short8v b = xtf[(long)tile * 64 + l];
    float4v zz = {0.f, 0.f, 0.f, 0.f};

    for (int k = 0; k < K; ++k) {
        float4v d0 = __builtin_amdgcn_mfma_f32_16x16x32_bf16(wtf[(2 * k + 0) * 64 + l], b, zz, 0, 0, 0);
        float4v d1 = __builtin_amdgcn_mfma_f32_16x16x32_bf16(wtf[(2 * k + 1) * 64 + l], b, zz, 0, 0, 0);
        unsigned* lr = &lds[node * RS + k * 16];
        lr[2 * g]     = pk2(d0[0], d0[1]);   // e = 4g, 4g+1
        lr[2 * g + 1] = pk2(d0[2], d0[3]);   // e = 4g+2, 4g+3
        lr[8 + 2 * g]     = pk2(d1[0], d1[1]);  // e = 16+4g..
        lr[8 + 2 * g + 1] = pk2(d1[2], d1[3]);
    }
    __syncthreads();

    unsigned* yb = y + (long)tile * (16 * K * 16);
    constexpr int TOT = 16 * K * 16;
    for (int off = l * 4; off < TOT; off += 256) {
        int nd = off / (K * 16);
        int rem = off - nd * (K * 16);
        const unsigned* lp = &lds[nd * RS + rem];
        uint4 v = make_uint4(lp[0], lp[1], lp[2], lp[3]);
        *(uint4*)(yb + off) = v;
    }
}

// per (edge, e): 4-tap bilinear blend of gathered bf16 y rows, atomic scatter
template<int KS>
__global__ void edge_y_k(const int* __restrict__ src, const int* __restrict__ dst,
                         const float* __restrict__ attr, const bf16_t* __restrict__ y,
                         float* __restrict__ agg) {
    long tid = (long)blockIdx.x * 256 + threadIdx.x;
    if (tid >= (long)NE * DD) return;
    int e = (int)(tid & (DD - 1));
    int ed = (int)(tid >> 5);
    const int K = KS * KS;
    float u0 = attr[2 * ed], u1 = attr[2 * ed + 1];
    float v0 = u0 * (KS - 1), v1 = u1 * (KS - 1);
    float fb0 = floorf(v0), fb1 = floorf(v1);
    float f0 = v0 - fb0, f1 = v1 - fb1;
    int i0 = min((int)fb0, KS - 1), i1 = min((int)fb1, KS - 1);
    int j0 = min(i0 + 1, KS - 1), j1 = min(i1 + 1, KS - 1);
    int s = src[ed];
    long base = (long)s * (K * DD) + e;
    float y00 = bf2f(y[base + (i0 + i1 * KS) * DD]);
    float y10 = bf2f(y[base + (j0 + i1 * KS) * DD]);
    float y01 = bf2f(y[base + (i0 + j1 * KS) * DD]);
    float y11 = bf2f(y[base + (j0 + j1 * KS) * DD]);
    float m = (1.f - f0) * (1.f - f1) * y00 + f0 * (1.f - f1) * y10
            + (1.f - f0) * f1 * y01 + f0 * f1 * y11;
    atomicAdd(&agg[(long)dst[ed] * DD + e], m);
}

// h[n,e] = elu(agg/max(cnt,1) + x@root + bias); root matvec via shfl
__global__ __launch_bounds__(256) void fin_k(
        const float* __restrict__ agg, const float* __restrict__ cnt,
        const float* __restrict__ xin, const float* __restrict__ root,
        const float* __restrict__ bias, float* __restrict__ h) {
    const int lane = threadIdx.x & 31;
    const int grp = threadIdx.x >> 5;
    const int n = blockIdx.x * 8 + grp;
    if (n >= NN) return;
    float c = cnt[n]; if (c < 1.f) c = 1.f;
    float xv = xin[(long)n * DD + lane];
    float racc = 0.f;
#pragma unroll
    for (int d = 0; d < DD; ++d)
        racc = fmaf(__shfl(xv, d, 32), root[d * DD + lane], racc);
    float v = agg[(long)n * DD + lane] / c + racc + bias[lane];
    h[(long)n * DD + lane] = v > 0.f ? v : expm1f(v);
}

// fused 2-layer MLP head: one 32-lane group per node
__global__ __launch_bounds__(256) void mlp_k(
        const float* __restrict__ h, const float* __restrict__ w1,
        const float* __restrict__ b1, const float* __restrict__ w2,
        const float* __restrict__ b2, float* __restrict__ out) {
    const int lane = threadIdx.x & 31;
    const int grp = threadIdx.x >> 5;
    const int n = blockIdx.x * 8 + grp;
    if (n >= NN) return;
    float hv = h[(long)n * DD + lane];
    float t = b1[lane];
#pragma unroll
    for (int d = 0; d < DD; ++d)
        t = fmaf(__shfl(hv, d, 32), w1[d * DD + lane], t);
    t = fmaxf(t, 0.f);
    int c = lane & (CC - 1);
    float o = 0.f;
#pragma unroll
    for (int d = 0; d < DD; ++d)
        o = fmaf(__shfl(t, d, 32), w2[d * CC + c], o);
    o += b2[c];
    o = fmaxf(o, 0.f);
    if (lane < CC) out[(long)n * CC + lane] = o;
}

extern "C" void kernel_launch(void* const* d_in, const int* in_sizes, int n_in,
                              void* d_out, int out_size, void* d_ws, size_t ws_size,
                              hipStream_t stream) {
    const float* x     = (const float*)d_in[0];
    const int*   ei    = (const int*)d_in[1];
    const float* attr  = (const float*)d_in[2];
    const float* W1    = (const float*)d_in[3];
    const float* root1 = (const float*)d_in[4];
    const float* bias1 = (const float*)d_in[5];
    const float* W2    = (const float*)d_in[6];
    const float* root2 = (const float*)d_in[7];
    const float* bias2 = (const float*)d_in[8];
    const float* m1w   = (const float*)d_in[9];
    const float* m1b   = (const float*)d_in[10];
    const float* m2w   = (const float*)d_in[11];
    const float* m2b   = (const float*)d_in[12];
    float* out = (float*)d_out;

    const int* srcp = ei;
    const int* dstp = ei + NE;

    // ws: cnt(NN f32) | agg(NN*32 f32) | h1(NN*32 f32) | xtf(NN*32 bf16)
    //     | wtf1(9*2*64*8 bf16) | wtf2(25*2*64*8 bf16) | y(NN*25*32 bf16)
    // h2 overlays y (fin<2> runs after edge<5> finished reading y).
    float* cnt  = (float*)d_ws;
    float* agg  = cnt + NN;
    float* h1   = agg + (size_t)NN * DD;
    bf16_t* xtf = (bf16_t*)(h1 + (size_t)NN * DD);
    bf16_t* wtf1 = xtf + (size_t)NN * DD;
    bf16_t* wtf2 = wtf1 + 9 * 2 * 64 * 8;
    bf16_t* y   = wtf2 + 25 * 2 * 64 * 8;
    float* h2   = (float*)y;
    // total ~ 0.4 + 12.8 + 12.8 + 6.4 + 0.11 + 160 = 192.5 MB

    const unsigned gn = (NN + 7) / 8;
    const unsigned gt = NN / 16;  // 6250, exact

    zero_k<<<gblocks(NN + (long)NN * DD), 256, 0, stream>>>(cnt, NN + (long)NN * DD);
    count_k<<<gblocks(NE), 256, 0, stream>>>(dstp, cnt);

    castx_k<<<gblocks(NN * 4), 256, 0, stream>>>(x, xtf);
    castw_k<<<gblocks(9 * 2 * 64), 256, 0, stream>>>(W1, wtf1, 9);
    castw_k<<<gblocks(25 * 2 * 64), 256, 0, stream>>>(W2, wtf2, 25);

    // ---- layer 1 (ksize=3, K=9) ----
    ymm_k<9><<<gt, 64, 0, stream>>>((const short8v*)xtf, (const short8v*)wtf1, (unsigned*)y);
    edge_y_k<3><<<gblocks((long)NE * DD), 256, 0, stream>>>(srcp, dstp, attr, y, agg);
    fin_k<<<gn, 256, 0, stream>>>(agg, cnt, x, root1, bias1, h1);

    // ---- layer 2 (ksize=5, K=25) ----
    castx_k<<<gblocks(NN * 4), 256, 0, stream>>>(h1, xtf);
    zero_k<<<gblocks((long)NN * DD), 256, 0, stream>>>(agg, (long)NN * DD);
    ymm_k<25><<<gt, 64, 0, stream>>>((const short8v*)xtf, (const short8v*)wtf2, (unsigned*)y);
    edge_y_k<5><<<gblocks((long)NE * DD), 256, 0, stream>>>(srcp, dstp, attr, y, agg);
    fin_k<<<gn, 256, 0, stream>>>(agg, cnt, h1, root2, bias2, h2);

    // ---- fused MLP head ----
    mlp_k<<<gn, 256, 0, stream>>>(h2, m1w, m1b, m2w, m2b, out);
}